// Round 19
// baseline (1237.386 us; speedup 1.0000x reference)
//
#include <hip/hip_runtime.h>
#include <hip/hip_bf16.h>

// R19 — DIAGNOSTIC+FIX: (a) nt loads removed; (b) fused kernel body repeated
// 4x inside ONE dispatch so it exceeds the ~330 us fills and surfaces in the
// top-5 counter window with FETCH/VALUBusy/Occupancy.  T_fused' = (dur-675)/4.

#define BN      32768   // B*N rows
#define NCOL    4096    // N
#define MAX_NBR 64      // Binomial(4096,0.004): mean 16.4, P(deg>64) ~ 1e-19

#define WS_NBR 0                       // u16 [BN][64]   (4 MB)
#define WS_DEG (4*1024*1024)           // int [BN]       (128 KB)
#define WS_H0  (WS_DEG + 131072)       // f32 [BN][64]   (8 MB)
#define WS_H1  (WS_H0 + 8*1024*1024)   // f32 [BN][32]   (4 MB)

__global__ __launch_bounds__(256) void fused_csr_layer0_kernel(
    const float* __restrict__ adj,
    const float* __restrict__ x,        // [BN][128]
    const float* __restrict__ Ws, const float* __restrict__ Wn,   // [128][64]
    const float* __restrict__ bias,     // [64]
    unsigned short* __restrict__ nbr,   // [BN][MAX_NBR]
    int* __restrict__ deg,              // [BN]
    float* __restrict__ h0)             // [BN][64]
{
    __shared__ int s_cnt;
    __shared__ unsigned short s_list[MAX_NBR];
    __shared__ float s_self[128];
    __shared__ float s_part[4][128];
    __shared__ float s_neigh[128];

    const int tid  = threadIdx.x;
    const int wave = tid >> 6, lane = tid & 63;
    const int row  = ((blockIdx.x & 7) << 12) | (blockIdx.x >> 3);  // batch -> XCD
    const int jbase = row & ~(NCOL - 1);
    const uint4* arow = reinterpret_cast<const uint4*>(adj + (size_t)row * NCOL);

    for (int rep = 0; rep < 4; ++rep) {          // idempotent 4x body (diagnostic)
        if (tid == 0) s_cnt = 0;
        __syncthreads();

        // ---- scan: 4 hoisted PLAIN loads per wave (nt removed), then process ----
        uint4 q[4];
        #pragma unroll
        for (int t = 0; t < 4; ++t)
            q[t] = arow[(wave * 4 + t) * 64 + lane];
        float2 sf;
        if (wave == 0) sf = *(const float2*)(x + (size_t)row * 128 + 2 * lane);

        #pragma unroll
        for (int t = 0; t < 4; ++t) {
            if (q[t].x | q[t].y | q[t].z | q[t].w) {   // values exactly {0f,1f}
                const int c4 = ((wave * 4 + t) * 64 + lane) * 4;
                if (q[t].x) { int p = atomicAdd(&s_cnt, 1);
                              if (p < MAX_NBR) s_list[p] = (unsigned short)(c4    ); }
                if (q[t].y) { int p = atomicAdd(&s_cnt, 1);
                              if (p < MAX_NBR) s_list[p] = (unsigned short)(c4 + 1); }
                if (q[t].z) { int p = atomicAdd(&s_cnt, 1);
                              if (p < MAX_NBR) s_list[p] = (unsigned short)(c4 + 2); }
                if (q[t].w) { int p = atomicAdd(&s_cnt, 1);
                              if (p < MAX_NBR) s_list[p] = (unsigned short)(c4 + 3); }
            }
        }
        if (wave == 0) { s_self[2 * lane] = sf.x; s_self[2 * lane + 1] = sf.y; }
        __syncthreads();

        const int d   = s_cnt;
        const int cnt = d < MAX_NBR ? d : MAX_NBR;
        const float dinv = 1.0f / (float)(d > 1 ? d : 1);

        if (tid < cnt) nbr[(size_t)row * MAX_NBR + tid] = s_list[tid];
        if (tid == 0) deg[row] = d;

        // ---- layer 0 gather: 4 wave-streams ----
        float n0 = 0.f, n1 = 0.f;
        for (int t = wave; t < cnt; t += 4) {
            const int j = jbase + (int)s_list[t];
            const float2 f = *(const float2*)(x + (size_t)j * 128 + 2 * lane);
            n0 += f.x; n1 += f.y;
        }
        s_part[wave][2 * lane]     = n0;
        s_part[wave][2 * lane + 1] = n1;
        __syncthreads();

        if (tid < 128)
            s_neigh[tid] = (s_part[0][tid] + s_part[1][tid] +
                            s_part[2][tid] + s_part[3][tid]) * dinv;
        __syncthreads();

        if (wave == 0) {
            const int o = lane;
            float acc = 0.f;
            #pragma unroll 8
            for (int k = 0; k < 128; ++k) {
                acc = fmaf(s_self[k],  Ws[k * 64 + o], acc);
                acc = fmaf(s_neigh[k], Wn[k * 64 + o], acc);
            }
            h0[(size_t)row * 64 + o] = fmaxf(acc + bias[o], 0.f);
        }
        __syncthreads();
    }
}

// ---------- layers 1,2: unchanged (R15/R18 form) ----------
template<int D_IN, int D_OUT>
__global__ __launch_bounds__(256) void gather_layer_kernel(
    const float* __restrict__ hin,
    const unsigned short* __restrict__ nbr,
    const int* __restrict__ deg,
    const float* __restrict__ Ws, const float* __restrict__ Wn,
    const float* __restrict__ bias,
    float* __restrict__ hout)
{
    constexpr int SUB = (D_IN >= 64) ? 1 : (64 / D_IN);
    constexpr int KPL = (D_IN + 63) / 64;
    constexpr int NW  = 4 * SUB;
    __shared__ float s_self[D_IN];
    __shared__ float s_part[NW][D_IN];
    __shared__ float s_neigh[D_IN];

    const int tid  = threadIdx.x;
    const int wave = tid >> 6, lane = tid & 63;
    const int sub  = (D_IN < 64) ? (lane / D_IN) : 0;
    const int sl   = (D_IN < 64) ? (lane % D_IN) : lane;
    const int strm = wave * SUB + sub;
    const int row  = ((blockIdx.x & 7) << 12) | (blockIdx.x >> 3);
    const int jbase = row & ~(NCOL - 1);

    const int d   = deg[row];
    const int cnt = d < MAX_NBR ? d : MAX_NBR;
    const float dinv = 1.0f / (float)(d > 1 ? d : 1);

    int mycol = 0;
    if (lane < cnt) mycol = nbr[(size_t)row * MAX_NBR + lane];

    if (wave == 0) {
        if constexpr (KPL == 2) {
            const float2 f = *(const float2*)(hin + (size_t)row * D_IN + 2 * lane);
            s_self[2 * lane] = f.x; s_self[2 * lane + 1] = f.y;
        } else {
            if (lane < D_IN) s_self[lane] = hin[(size_t)row * D_IN + lane];
        }
    }

    float nv[KPL];
    #pragma unroll
    for (int i = 0; i < KPL; ++i) nv[i] = 0.f;
    for (int t = strm; t < cnt; t += NW) {
        const int j = jbase + __shfl(mycol, t, 64);
        if constexpr (KPL == 2) {
            const float2 f = *(const float2*)(hin + (size_t)j * D_IN + 2 * lane);
            nv[0] += f.x; nv[1] += f.y;
        } else {
            nv[0] += hin[(size_t)j * D_IN + sl];
        }
    }
    if constexpr (KPL == 2) {
        s_part[strm][2 * lane]     = nv[0];
        s_part[strm][2 * lane + 1] = nv[1];
    } else {
        s_part[strm][sl] = nv[0];
    }
    __syncthreads();

    if (tid < D_IN) {
        float s = 0.f;
        #pragma unroll
        for (int p = 0; p < NW; ++p) s += s_part[p][tid];
        s_neigh[tid] = s * dinv;
    }
    __syncthreads();

    if (wave == 0) {
        constexpr int SEG  = 64 / D_OUT;
        constexpr int KSEG = D_IN / SEG;
        const int o = lane % D_OUT, seg = lane / D_OUT;
        float acc = 0.f;
        #pragma unroll 8
        for (int kk = 0; kk < KSEG; ++kk) {
            const int k = seg * KSEG + kk;
            acc = fmaf(s_self[k],  Ws[k * D_OUT + o], acc);
            acc = fmaf(s_neigh[k], Wn[k * D_OUT + o], acc);
        }
        if constexpr (SEG == 2) acc += __shfl_xor(acc, 32, 64);
        if (seg == 0)
            hout[(size_t)row * D_OUT + o] = fmaxf(acc + bias[o], 0.f);
    }
}

extern "C" void kernel_launch(void* const* d_in, const int* in_sizes, int n_in,
                              void* d_out, int out_size, void* d_ws, size_t ws_size,
                              hipStream_t stream) {
    const float* x   = (const float*)d_in[0];
    const float* adj = (const float*)d_in[1];
    const float* Ws0 = (const float*)d_in[2]; const float* Wn0 = (const float*)d_in[3];
    const float* b0  = (const float*)d_in[4];
    const float* Ws1 = (const float*)d_in[5]; const float* Wn1 = (const float*)d_in[6];
    const float* b1  = (const float*)d_in[7];
    const float* Ws2 = (const float*)d_in[8]; const float* Wn2 = (const float*)d_in[9];
    const float* b2  = (const float*)d_in[10];

    char* ws = (char*)d_ws;
    unsigned short* nbr = (unsigned short*)(ws + WS_NBR);
    int*   deg = (int*)(ws + WS_DEG);
    float* h0  = (float*)(ws + WS_H0);
    float* h1  = (float*)(ws + WS_H1);

    fused_csr_layer0_kernel<<<BN, 256, 0, stream>>>(
        adj, x, Ws0, Wn0, b0, nbr, deg, h0);
    gather_layer_kernel<64, 32><<<BN, 256, 0, stream>>>(
        h0, nbr, deg, Ws1, Wn1, b1, h1);
    gather_layer_kernel<32, 32><<<BN, 256, 0, stream>>>(
        h1, nbr, deg, Ws2, Wn2, b2, (float*)d_out);
}

// Round 20
// 810.493 us; speedup vs baseline: 1.5267x; 1.5267x over previous
//
#include <hip/hip_runtime.h>
#include <hip/hip_bf16.h>

#define BN      32768   // B*N rows
#define NCOL    4096    // N
#define MAX_NBR 64      // Binomial(4096,0.004): mean 16.4, P(deg>64) ~ 1e-19

#define WS_NBR 0                       // u16 [BN][64]   (4 MB)
#define WS_DEG (4*1024*1024)           // int [BN]       (128 KB)
#define WS_H0  (WS_DEG + 131072)       // f32 [BN][64]   (8 MB)
#define WS_H1  (WS_H0 + 8*1024*1024)   // f32 [BN][32]   (4 MB)

// ---------- kernel 1: FUSED adj-scan + CSR + layer 0, W-AMORTIZED GEMV ----------
// 4 rows/block (wave w scans+gathers row base+w). GEMV k-split across waves:
// each W load (2 per k) feeds all 4 rows' accumulators -> 16 W-loads/row
// instead of 256 (R19 counters: 859 GB/s HBM, 27% VALU -> GEMV L2 latency was
// the bottleneck, not bandwidth). Partials reduced via LDS.
__global__ __launch_bounds__(256) void fused_csr_layer0_kernel(
    const float* __restrict__ adj,
    const float* __restrict__ x,        // [BN][128]
    const float* __restrict__ Ws, const float* __restrict__ Wn,   // [128][64]
    const float* __restrict__ bias,     // [64]
    unsigned short* __restrict__ nbr,   // [BN][MAX_NBR]
    int* __restrict__ deg,              // [BN]
    float* __restrict__ h0)             // [BN][64]
{
    __shared__ int s_cnt[4];
    __shared__ unsigned short s_list[4][MAX_NBR];
    __shared__ alignas(16) float s_self[4][128];
    __shared__ alignas(16) float s_neigh[4][128];
    __shared__ float s_gemv[4][4][64];  // [k-quarter wave][row][o]

    const int wave = threadIdx.x >> 6, lane = threadIdx.x & 63;
    const int row  = (((blockIdx.x & 7) << 12) | ((blockIdx.x >> 3) << 2)) + wave;
    const int jbase = row & ~(NCOL - 1);

    if (lane == 0) s_cnt[wave] = 0;     // wave-local LDS: program order suffices

    // ---- scan own row: 2 groups of 8 hoisted loads (one vmcnt drain each) ----
    const uint4* arow = reinterpret_cast<const uint4*>(adj + (size_t)row * NCOL);
    #pragma unroll
    for (int g = 0; g < 2; ++g) {
        uint4 q[8];
        #pragma unroll
        for (int t = 0; t < 8; ++t) q[t] = arow[(g * 8 + t) * 64 + lane];
        #pragma unroll
        for (int t = 0; t < 8; ++t) {
            if (q[t].x | q[t].y | q[t].z | q[t].w) {   // values exactly {0f,1f}
                const int c4 = ((g * 8 + t) * 64 + lane) * 4;
                if (q[t].x) { int p = atomicAdd(&s_cnt[wave], 1);
                              if (p < MAX_NBR) s_list[wave][p] = (unsigned short)(c4    ); }
                if (q[t].y) { int p = atomicAdd(&s_cnt[wave], 1);
                              if (p < MAX_NBR) s_list[wave][p] = (unsigned short)(c4 + 1); }
                if (q[t].z) { int p = atomicAdd(&s_cnt[wave], 1);
                              if (p < MAX_NBR) s_list[wave][p] = (unsigned short)(c4 + 2); }
                if (q[t].w) { int p = atomicAdd(&s_cnt[wave], 1);
                              if (p < MAX_NBR) s_list[wave][p] = (unsigned short)(c4 + 3); }
            }
        }
    }

    const float2 sf = *(const float2*)(x + (size_t)row * 128 + 2 * lane);
    const int d   = s_cnt[wave];        // own wave's atomics complete in order
    const int cnt = d < MAX_NBR ? d : MAX_NBR;
    const float dinv = 1.0f / (float)(d > 1 ? d : 1);

    if (lane < cnt) nbr[(size_t)row * MAX_NBR + lane] = s_list[wave][lane];
    if (lane == 0) deg[row] = d;

    // ---- gather own row's neighbors (x slice L2-resident via XCD swizzle) ----
    float n0 = 0.f, n1 = 0.f;
    for (int t = 0; t < cnt; ++t) {
        const int j = jbase + (int)s_list[wave][t];
        const float2 f = *(const float2*)(x + (size_t)j * 128 + 2 * lane);
        n0 += f.x; n1 += f.y;
    }
    s_self[wave][2 * lane]      = sf.x;
    s_self[wave][2 * lane + 1]  = sf.y;
    s_neigh[wave][2 * lane]     = n0 * dinv;
    s_neigh[wave][2 * lane + 1] = n1 * dinv;
    __syncthreads();

    // ---- GEMV, k-split: wave w covers k in [32w, 32w+32), all 4 rows ----
    float acc[4] = { 0.f, 0.f, 0.f, 0.f };
    const int k0 = wave * 32;
    #pragma unroll
    for (int gg = 0; gg < 8; ++gg) {
        const int k = k0 + gg * 4;
        float w_s[4], w_n[4];
        #pragma unroll
        for (int u = 0; u < 4; ++u) {
            w_s[u] = Ws[(k + u) * 64 + lane];   // 256B coalesced, reused by 4 rows
            w_n[u] = Wn[(k + u) * 64 + lane];
        }
        #pragma unroll
        for (int r = 0; r < 4; ++r) {
            const float4 sv = *(const float4*)&s_self[r][k];    // LDS b128 broadcast
            const float4 nv = *(const float4*)&s_neigh[r][k];
            acc[r] = fmaf(sv.x, w_s[0], acc[r]);  acc[r] = fmaf(nv.x, w_n[0], acc[r]);
            acc[r] = fmaf(sv.y, w_s[1], acc[r]);  acc[r] = fmaf(nv.y, w_n[1], acc[r]);
            acc[r] = fmaf(sv.z, w_s[2], acc[r]);  acc[r] = fmaf(nv.z, w_n[2], acc[r]);
            acc[r] = fmaf(sv.w, w_s[3], acc[r]);  acc[r] = fmaf(nv.w, w_n[3], acc[r]);
        }
    }
    #pragma unroll
    for (int r = 0; r < 4; ++r) s_gemv[wave][r][lane] = acc[r];
    __syncthreads();

    // ---- finalize: wave r reduces row r over the 4 k-quarters ----
    const float v = s_gemv[0][wave][lane] + s_gemv[1][wave][lane] +
                    s_gemv[2][wave][lane] + s_gemv[3][wave][lane] + bias[lane];
    h0[(size_t)row * 64 + lane] = fmaxf(v, 0.f);
}

// ---------- layers 1,2: unchanged (R15/R18 form) ----------
template<int D_IN, int D_OUT>
__global__ __launch_bounds__(256) void gather_layer_kernel(
    const float* __restrict__ hin,
    const unsigned short* __restrict__ nbr,
    const int* __restrict__ deg,
    const float* __restrict__ Ws, const float* __restrict__ Wn,
    const float* __restrict__ bias,
    float* __restrict__ hout)
{
    constexpr int SUB = (D_IN >= 64) ? 1 : (64 / D_IN);
    constexpr int KPL = (D_IN + 63) / 64;
    constexpr int NW  = 4 * SUB;
    __shared__ float s_self[D_IN];
    __shared__ float s_part[NW][D_IN];
    __shared__ float s_neigh[D_IN];

    const int tid  = threadIdx.x;
    const int wave = tid >> 6, lane = tid & 63;
    const int sub  = (D_IN < 64) ? (lane / D_IN) : 0;
    const int sl   = (D_IN < 64) ? (lane % D_IN) : lane;
    const int strm = wave * SUB + sub;
    const int row  = ((blockIdx.x & 7) << 12) | (blockIdx.x >> 3);
    const int jbase = row & ~(NCOL - 1);

    const int d   = deg[row];
    const int cnt = d < MAX_NBR ? d : MAX_NBR;
    const float dinv = 1.0f / (float)(d > 1 ? d : 1);

    int mycol = 0;
    if (lane < cnt) mycol = nbr[(size_t)row * MAX_NBR + lane];

    if (wave == 0) {
        if constexpr (KPL == 2) {
            const float2 f = *(const float2*)(hin + (size_t)row * D_IN + 2 * lane);
            s_self[2 * lane] = f.x; s_self[2 * lane + 1] = f.y;
        } else {
            if (lane < D_IN) s_self[lane] = hin[(size_t)row * D_IN + lane];
        }
    }

    float nv[KPL];
    #pragma unroll
    for (int i = 0; i < KPL; ++i) nv[i] = 0.f;
    for (int t = strm; t < cnt; t += NW) {
        const int j = jbase + __shfl(mycol, t, 64);
        if constexpr (KPL == 2) {
            const float2 f = *(const float2*)(hin + (size_t)j * D_IN + 2 * lane);
            nv[0] += f.x; nv[1] += f.y;
        } else {
            nv[0] += hin[(size_t)j * D_IN + sl];
        }
    }
    if constexpr (KPL == 2) {
        s_part[strm][2 * lane]     = nv[0];
        s_part[strm][2 * lane + 1] = nv[1];
    } else {
        s_part[strm][sl] = nv[0];
    }
    __syncthreads();

    if (tid < D_IN) {
        float s = 0.f;
        #pragma unroll
        for (int p = 0; p < NW; ++p) s += s_part[p][tid];
        s_neigh[tid] = s * dinv;
    }
    __syncthreads();

    if (wave == 0) {
        constexpr int SEG  = 64 / D_OUT;
        constexpr int KSEG = D_IN / SEG;
        const int o = lane % D_OUT, seg = lane / D_OUT;
        float acc = 0.f;
        #pragma unroll 8
        for (int kk = 0; kk < KSEG; ++kk) {
            const int k = seg * KSEG + kk;
            acc = fmaf(s_self[k],  Ws[k * D_OUT + o], acc);
            acc = fmaf(s_neigh[k], Wn[k * D_OUT + o], acc);
        }
        if constexpr (SEG == 2) acc += __shfl_xor(acc, 32, 64);
        if (seg == 0)
            hout[(size_t)row * D_OUT + o] = fmaxf(acc + bias[o], 0.f);
    }
}

extern "C" void kernel_launch(void* const* d_in, const int* in_sizes, int n_in,
                              void* d_out, int out_size, void* d_ws, size_t ws_size,
                              hipStream_t stream) {
    const float* x   = (const float*)d_in[0];
    const float* adj = (const float*)d_in[1];
    const float* Ws0 = (const float*)d_in[2]; const float* Wn0 = (const float*)d_in[3];
    const float* b0  = (const float*)d_in[4];
    const float* Ws1 = (const float*)d_in[5]; const float* Wn1 = (const float*)d_in[6];
    const float* b1  = (const float*)d_in[7];
    const float* Ws2 = (const float*)d_in[8]; const float* Wn2 = (const float*)d_in[9];
    const float* b2  = (const float*)d_in[10];

    char* ws = (char*)d_ws;
    unsigned short* nbr = (unsigned short*)(ws + WS_NBR);
    int*   deg = (int*)(ws + WS_DEG);
    float* h0  = (float*)(ws + WS_H0);
    float* h1  = (float*)(ws + WS_H1);

    fused_csr_layer0_kernel<<<BN / 4, 256, 0, stream>>>(
        adj, x, Ws0, Wn0, b0, nbr, deg, h0);
    gather_layer_kernel<64, 32><<<BN, 256, 0, stream>>>(
        h0, nbr, deg, Ws1, Wn1, b1, h1);
    gather_layer_kernel<32, 32><<<BN, 256, 0, stream>>>(
        h1, nbr, deg, Ws2, Wn2, b2, (float*)d_out);
}